// Round 4
// baseline (246.737 us; speedup 1.0000x reference)
//
#include <hip/hip_runtime.h>

typedef short short8 __attribute__((ext_vector_type(8)));
typedef float f32x4 __attribute__((ext_vector_type(4)));

#define NV 131072
#define KK 27
#define CH 64

__device__ inline unsigned short f2b(float f) {
    unsigned u = __float_as_uint(f);
    u += 0x7fffu + ((u >> 16) & 1u);   // round-to-nearest-even
    return (unsigned short)(u >> 16);
}

// feat f32 [N,C] -> bf16 bits [N,C]
__global__ void prep_feat(const float* __restrict__ feat, unsigned short* __restrict__ featb) {
    int i = blockIdx.x * blockDim.x + threadIdx.x;
    float4 v = reinterpret_cast<const float4*>(feat)[i];
    ushort4 o;
    o.x = f2b(v.x); o.y = f2b(v.y); o.z = f2b(v.z); o.w = f2b(v.w);
    reinterpret_cast<ushort4*>(featb)[i] = o;
}

// W [K][Ci][Co] f32 -> Wt [K][Co][Ci] bf16
__global__ void prep_w(const float* __restrict__ W1, const float* __restrict__ W2,
                       unsigned short* __restrict__ wt1, unsigned short* __restrict__ wt2) {
    int id = blockIdx.x * blockDim.x + threadIdx.x;
    const float* W = W1; unsigned short* wt = wt1;
    int e = id;
    if (e >= KK * CH * CH) { e -= KK * CH * CH; W = W2; wt = wt2; }
    int k = e >> 12, o = (e >> 6) & 63, c = e & 63;
    wt[e] = f2b(W[k * CH * CH + c * CH + o]);
}

__device__ inline void gld16(const void* gsrc, void* ldst) {
    __builtin_amdgcn_global_load_lds(
        (const __attribute__((address_space(1))) unsigned int*)gsrc,
        (__attribute__((address_space(3))) unsigned int*)ldst,
        16, 0, 0);
}

// Block = 256 thr = 4 INDEPENDENT waves (no barriers). Wave owns 64 rows x 64 cols.
// Per-wave private LDS A-ring: 2 slots x 8 KB, layout [rt][h][kg][lr][16B] (linear in
// lane for both the global_load_lds dest and the ds_read_b128 fragments -> conflict-free).
// B double-buffered in registers (L1/L2-hot). Counted vmcnt, never drained in-loop.
// Per fenced iteration VMEM = 8 B-loads + 8 A-stage + 4 idx = 20 -> vmcnt(20) completes
// tap t's stage while keeping tap t+1's stage + B(t+1) + idx in flight.
template <int EPI>
__global__ __launch_bounds__(256, 2) void conv_layer(
    const unsigned short* __restrict__ xb,   // [N,C] bf16 input
    const unsigned short* __restrict__ wt,   // [K,Co,Ci] bf16 transposed weights
    const float* __restrict__ bias,          // [C]
    const int* __restrict__ nbr,             // [N,K]
    const float* __restrict__ resid,         // [N,C] f32 (EPI==1)
    unsigned short* __restrict__ outb,       // bf16 out (EPI==0)
    float* __restrict__ outf)                // f32 out (EPI==1)
{
    __shared__ char lds[4 * 2 * 8192];       // [wave][slot][8KB] = 64 KB
    const int wid  = threadIdx.x >> 6;
    const int lane = threadIdx.x & 63;
    const int lr   = lane & 15;
    const int kg   = lane >> 4;
    const int rowbase = blockIdx.x * 256 + wid * 64;

    const int* np[4];
    #pragma unroll
    for (int rt = 0; rt < 4; ++rt)
        np[rt] = nbr + (size_t)(rowbase + rt * 16 + lr) * KK;

    char* const myl = lds + wid * 16384;

    int idxs[3][4];                           // 3-slot idx rotation (static under unroll)
    #pragma unroll
    for (int rt = 0; rt < 4; ++rt) {
        idxs[0][rt] = np[rt][0];
        idxs[1][rt] = np[rt][1];
        idxs[2][rt] = np[rt][2];
    }

    f32x4 acc[4][4];
    #pragma unroll
    for (int rt = 0; rt < 4; ++rt)
        #pragma unroll
        for (int nt = 0; nt < 4; ++nt)
            acc[rt][nt] = (f32x4){0.f, 0.f, 0.f, 0.f};

    short8 bb[2][8];                          // B double buffer (static indices)

    auto stage = [&](int t, const int* id) {  // 8 gld16: rows [rt*16+lr], full 128B/row
        char* ab = myl + (t & 1) * 8192;
        #pragma unroll
        for (int rt = 0; rt < 4; ++rt) {
            const unsigned short* g = xb + (size_t)id[rt] * CH + kg * 8;
            gld16(g,      ab + rt * 2048);          // h=0: chunks kg
            gld16(g + 32, ab + rt * 2048 + 1024);   // h=1: chunks kg+4
        }
    };
    auto loadB = [&](short8* d, const unsigned short* w) {
        #pragma unroll
        for (int nt = 0; nt < 4; ++nt) {
            d[nt]     = *reinterpret_cast<const short8*>(w + (nt * 16 + lr) * CH + kg * 8);
            d[nt + 4] = *reinterpret_cast<const short8*>(w + (nt * 16 + lr) * CH + kg * 8 + 32);
        }
    };

    // Prologue: stage taps 0,1; then (fenced after) idx(3) + B(0) -> exactly 20 VMEM
    // issued after A(0)'s last stage instr, matching the steady-state vmcnt(20).
    stage(0, idxs[0]);
    stage(1, idxs[1]);
    asm volatile("" ::: "memory");
    #pragma unroll
    for (int rt = 0; rt < 4; ++rt) idxs[0][rt] = np[rt][3];
    loadB(bb[0], wt);

    #pragma unroll
    for (int t = 0; t < KK; ++t) {
        // Counted wait: tap t's 8 stage instrs complete; newer 20 stay in flight.
        if (t < 24)      asm volatile("s_waitcnt vmcnt(20)" ::: "memory");
        else if (t < 26) asm volatile("s_waitcnt vmcnt(16)" ::: "memory");
        else             asm volatile("s_waitcnt vmcnt(8)" ::: "memory");

        const char* ab = myl + (t & 1) * 8192;
        short8 a[4][2];
        #pragma unroll
        for (int rt = 0; rt < 4; ++rt) {
            a[rt][0] = *reinterpret_cast<const short8*>(ab + rt * 2048 + kg * 256 + lr * 16);
            a[rt][1] = *reinterpret_cast<const short8*>(ab + rt * 2048 + 1024 + kg * 256 + lr * 16);
        }
        // Fragments landed in regs before this slot is re-staged below.
        asm volatile("s_waitcnt lgkmcnt(0)" ::: "memory");

        if (t + 1 < KK) loadB(bb[(t + 1) & 1], wt + (size_t)(t + 1) * CH * CH);
        if (t + 2 < KK) stage(t + 2, idxs[(t + 2) % 3]);
        if (t + 4 < KK) {
            #pragma unroll
            for (int rt = 0; rt < 4; ++rt) idxs[(t + 4) % 3][rt] = np[rt][t + 4];
        }

        #pragma unroll
        for (int rt = 0; rt < 4; ++rt)
            #pragma unroll
            for (int nt = 0; nt < 4; ++nt) {
                acc[rt][nt] = __builtin_amdgcn_mfma_f32_16x16x32_bf16(a[rt][0], bb[t & 1][nt],     acc[rt][nt], 0, 0, 0);
                acc[rt][nt] = __builtin_amdgcn_mfma_f32_16x16x32_bf16(a[rt][1], bb[t & 1][nt + 4], acc[rt][nt], 0, 0, 0);
            }
    }

    // Epilogue. D layout: col = nt*16 + lr, row = rowbase + rt*16 + kg*4 + i.
    #pragma unroll
    for (int rt = 0; rt < 4; ++rt) {
        const int row0 = rowbase + rt * 16 + kg * 4;
        #pragma unroll
        for (int nt = 0; nt < 4; ++nt) {
            int col = nt * 16 + lr;
            float bv = bias[col];
            #pragma unroll
            for (int i = 0; i < 4; ++i) {
                float v = acc[rt][nt][i] + bv;
                if (EPI == 0) {
                    v = fmaxf(v, 0.f);
                    outb[(size_t)(row0 + i) * CH + col] = f2b(v);
                } else {
                    v += resid[(size_t)(row0 + i) * CH + col];
                    v = fmaxf(v, 0.f);
                    outf[(size_t)(row0 + i) * CH + col] = v;
                }
            }
        }
    }
}

extern "C" void kernel_launch(void* const* d_in, const int* in_sizes, int n_in,
                              void* d_out, int out_size, void* d_ws, size_t ws_size,
                              hipStream_t stream) {
    const float* feat = (const float*)d_in[0];
    const float* W1   = (const float*)d_in[1];
    const float* b1   = (const float*)d_in[2];
    const float* W2   = (const float*)d_in[3];
    const float* b2   = (const float*)d_in[4];
    const int*   nbr  = (const int*)d_in[5];
    float* out = (float*)d_out;

    char* ws = (char*)d_ws;
    unsigned short* featb = (unsigned short*)ws;                              // 16.78 MB
    unsigned short* hb    = (unsigned short*)(ws + (size_t)NV * CH * 2);      // 16.78 MB
    unsigned short* wt1   = (unsigned short*)(ws + (size_t)NV * CH * 4);      // 216 KB
    unsigned short* wt2   = wt1 + KK * CH * CH;                               // 216 KB

    prep_feat<<<NV * CH / 4 / 256, 256, 0, stream>>>(feat, featb);
    prep_w<<<2 * KK * CH * CH / 256, 256, 0, stream>>>(W1, W2, wt1, wt2);
    conv_layer<0><<<NV / 256, 256, 0, stream>>>(featb, wt1, b1, nbr, nullptr, hb, nullptr);
    conv_layer<1><<<NV / 256, 256, 0, stream>>>(hb, wt2, b2, nbr, feat, nullptr, out);
}

// Round 5
// 227.817 us; speedup vs baseline: 1.0830x; 1.0830x over previous
//
#include <hip/hip_runtime.h>

typedef short short8 __attribute__((ext_vector_type(8)));
typedef float f32x4 __attribute__((ext_vector_type(4)));

#define NV 131072
#define KK 27
#define CH 64
#define NC 4      // channel chunks per conv
#define CE 16     // channels per chunk (chunk region = NV*CE*2B = 4.19 MB ~ one XCD L2)
// weight record padded to 32 elems (64B) per (chunk,tap,ocol); elems 16..31 are ZERO
#define WREC 32

#define FENCE asm volatile("" ::: "memory")

__device__ inline unsigned short f2b(float f) {
    unsigned u = __float_as_uint(f);
    u += 0x7fffu + ((u >> 16) & 1u);   // round-to-nearest-even
    return (unsigned short)(u >> 16);
}

// feat f32 [N][64] -> chunk-major bf16 xc[4][N][16]
__global__ void prep_featc(const float* __restrict__ feat, unsigned short* __restrict__ xc) {
    int tid = blockIdx.x * blockDim.x + threadIdx.x;   // N*16 threads
    int j = tid >> 4, u = tid & 15;
    float4 v = *reinterpret_cast<const float4*>(feat + j * CH + u * 4);
    int c = u >> 2, e0 = (u & 3) * 4;
    ushort4 o;
    o.x = f2b(v.x); o.y = f2b(v.y); o.z = f2b(v.z); o.w = f2b(v.w);
    *reinterpret_cast<ushort4*>(xc + ((size_t)c * NV + j) * CE + e0) = o;
}

// W [K][Ci][Co] f32 -> wt4 [NC][KK][64][WREC] bf16, e>=16 zeroed (both layers)
__global__ void prep_w4(const float* __restrict__ W1, const float* __restrict__ W2,
                        unsigned short* __restrict__ wt1, unsigned short* __restrict__ wt2) {
    int id = blockIdx.x * blockDim.x + threadIdx.x;    // 2*NC*KK*64*WREC
    const int PER = NC * KK * 64 * WREC;
    const float* W = W1; unsigned short* wt = wt1;
    int e = id;
    if (e >= PER) { e -= PER; W = W2; wt = wt2; }
    int ee = e & 31, o = (e >> 5) & 63, rest = e >> 11;
    int k = rest % KK, c = rest / KK;
    float v = (ee < CE) ? W[(k * CH + (c * CE + ee)) * CH + o] : 0.f;
    wt[e] = f2b(v);
}

__device__ inline void gld16(const void* gsrc, void* ldst) {
    __builtin_amdgcn_global_load_lds(
        (const __attribute__((address_space(1))) unsigned int*)gsrc,
        (__attribute__((address_space(3))) unsigned int*)ldst,
        16, 0, 0);
}

// 4 independent waves/block, wave owns 64 rows x 64 cols. 4 channel-chunk phases,
// acc persists across phases. Per-wave A ring: 4 slots x 2KB (64 rows x 32B).
// idx cached in LDS once. Counted vmcnt, per-iter VMEM = 4 B-loads + 2 A-stages.
template <int EPI>
__global__ __launch_bounds__(256, 2) void conv_phase(
    const unsigned short* __restrict__ xc,    // [NC][NV][CE] bf16 (chunk-major input)
    const unsigned short* __restrict__ wt4,   // [NC][KK][64][WREC] bf16
    const float* __restrict__ bias,           // [64]
    const int* __restrict__ nbr,              // [N][KK]
    const float* __restrict__ resid,          // [N][64] f32 (EPI==1)
    unsigned short* __restrict__ hc,          // EPI0 out: chunk-major [NC][NV][CE]
    float* __restrict__ outf)                 // EPI1 out: [N][64] f32
{
    __shared__ int  idxl[256 * KK];           // 27648 B
    __shared__ char aring[4][4][2048];        // 32768 B  [wave][slot][64 rows x 32B]
    const int tid  = threadIdx.x;
    const int wid  = tid >> 6;
    const int lane = tid & 63;
    const int lr   = lane & 15;
    const int kg   = lane >> 4;
    const int kgl  = kg & 1;

    // nbr rows of this block -> LDS (coalesced, row-major [256][27])
    #pragma unroll
    for (int e = 0; e < KK; ++e)
        idxl[e * 256 + tid] = nbr[(size_t)blockIdx.x * 256 * KK + e * 256 + tid];
    __syncthreads();

    const int* myidx = idxl + wid * 64 * KK;  // this wave's [64][KK]
    char* const ar = (char*)&aring[wid][0][0];

    f32x4 acc[4][4];
    #pragma unroll
    for (int rt = 0; rt < 4; ++rt)
        #pragma unroll
        for (int nt = 0; nt < 4; ++nt)
            acc[rt][nt] = (f32x4){0.f, 0.f, 0.f, 0.f};

    short8 b[2][4];

    auto loadB = [&](short8* d, const unsigned short* wc, int t) {
        #pragma unroll
        for (int nt = 0; nt < 4; ++nt)
            d[nt] = *reinterpret_cast<const short8*>(
                wc + ((size_t)(t * 64 + nt * 16 + lr)) * WREC + kg * 8);
    };
    // stage tap t: 2 gld16; instr s covers rows s*32..s*32+31 (lane l -> row s*32+(l>>1), half l&1)
    auto stage = [&](const unsigned short* xcc, int slot, int vi0, int vi1) {
        char* dst = ar + slot * 2048;
        gld16(xcc + (size_t)vi0 * CE + (lane & 1) * 8, dst + lane * 16);
        gld16(xcc + (size_t)vi1 * CE + (lane & 1) * 8, dst + 1024 + lane * 16);
    };

    #pragma unroll 1
    for (int c = 0; c < NC; ++c) {
        const unsigned short* xcc = xc  + (size_t)c * NV * CE;
        const unsigned short* wcc = wt4 + (size_t)c * KK * 64 * WREC;

        // prologue: stage taps 0,1,2 ; then B(0)  -> queue: [st0 2][st1 2][st2 2][B0 4]
        {
            int r0 = (lane >> 1) * KK, r1 = (32 + (lane >> 1)) * KK;
            int v00 = myidx[r0 + 0], v01 = myidx[r1 + 0];
            int v10 = myidx[r0 + 1], v11 = myidx[r1 + 1];
            int v20 = myidx[r0 + 2], v21 = myidx[r1 + 2];
            stage(xcc, 0, v00, v01); FENCE;
            stage(xcc, 1, v10, v11); FENCE;
            stage(xcc, 2, v20, v21); FENCE;
            loadB(b[0], wcc, 0); FENCE;
        }

        #pragma unroll
        for (int t = 0; t < KK; ++t) {
            // counted waits: guarantee stage(t) complete, keep newer loads in flight
            if      (t == 0)  asm volatile("s_waitcnt vmcnt(8)"  ::: "memory");
            else if (t == 1)  asm volatile("s_waitcnt vmcnt(12)" ::: "memory");
            else if (t == 2)  asm volatile("s_waitcnt vmcnt(16)" ::: "memory");
            else if (t == 24) asm volatile("s_waitcnt vmcnt(10)" ::: "memory");
            else if (t >= 25) asm volatile("s_waitcnt vmcnt(8)"  ::: "memory");
            else              asm volatile("s_waitcnt vmcnt(12)" ::: "memory");

            const char* ab = ar + (t & 3) * 2048;
            short8 a_[4];
            #pragma unroll
            for (int rt = 0; rt < 4; ++rt)
                a_[rt] = *reinterpret_cast<const short8*>(ab + (rt * 16 + lr) * 32 + kgl * 16);

            int vi0 = 0, vi1 = 0;
            if (t + 3 < KK) {
                vi0 = myidx[(lane >> 1) * KK + (t + 3)];
                vi1 = myidx[(32 + (lane >> 1)) * KK + (t + 3)];
            }
            asm volatile("s_waitcnt lgkmcnt(0)" ::: "memory");
            __builtin_amdgcn_sched_barrier(0);

            if (t + 1 < KK) { loadB(b[(t + 1) & 1], wcc, t + 1); }
            FENCE;
            if (t + 3 < KK) { stage(xcc, (t + 3) & 3, vi0, vi1); }
            FENCE;

            #pragma unroll
            for (int rt = 0; rt < 4; ++rt)
                #pragma unroll
                for (int nt = 0; nt < 4; ++nt)
                    acc[rt][nt] = __builtin_amdgcn_mfma_f32_16x16x32_bf16(
                        a_[rt], b[t & 1][nt], acc[rt][nt], 0, 0, 0);
        }
    }

    // Epilogue. D: col = nt*16+lr, row = base + rt*16 + kg*4 + i
    const int rowb = blockIdx.x * 256 + wid * 64;
    #pragma unroll
    for (int rt = 0; rt < 4; ++rt) {
        const int row0 = rowb + rt * 16 + kg * 4;
        #pragma unroll
        for (int nt = 0; nt < 4; ++nt) {
            int col = nt * 16 + lr;
            float bv = bias[col];
            #pragma unroll
            for (int i = 0; i < 4; ++i) {
                float v = acc[rt][nt][i] + bv;
                if (EPI == 0) {
                    v = fmaxf(v, 0.f);
                    // chunk-major: chunk = nt, e = lr
                    hc[((size_t)nt * NV + (row0 + i)) * CE + lr] = f2b(v);
                } else {
                    v += __builtin_nontemporal_load(resid + (size_t)(row0 + i) * CH + col);
                    v = fmaxf(v, 0.f);
                    __builtin_nontemporal_store(v, outf + (size_t)(row0 + i) * CH + col);
                }
            }
        }
    }
}

extern "C" void kernel_launch(void* const* d_in, const int* in_sizes, int n_in,
                              void* d_out, int out_size, void* d_ws, size_t ws_size,
                              hipStream_t stream) {
    const float* feat = (const float*)d_in[0];
    const float* W1   = (const float*)d_in[1];
    const float* b1   = (const float*)d_in[2];
    const float* W2   = (const float*)d_in[3];
    const float* b2   = (const float*)d_in[4];
    const int*   nbr  = (const int*)d_in[5];
    float* out = (float*)d_out;

    char* ws = (char*)d_ws;
    unsigned short* featc = (unsigned short*)ws;                               // 16.78 MB
    unsigned short* hcb   = (unsigned short*)(ws + (size_t)NV * CH * 2);       // 16.78 MB
    unsigned short* wt41  = (unsigned short*)(ws + (size_t)NV * CH * 4);       // 884 KB
    unsigned short* wt42  = wt41 + NC * KK * 64 * WREC;                        // 884 KB

    prep_featc<<<NV * 16 / 256, 256, 0, stream>>>(feat, featc);
    prep_w4<<<2 * NC * KK * 64 * WREC / 256, 256, 0, stream>>>(W1, W2, wt41, wt42);
    conv_phase<0><<<NV / 256, 256, 0, stream>>>(featc, wt41, b1, nbr, nullptr, hcb, nullptr);
    conv_phase<1><<<NV / 256, 256, 0, stream>>>(hcb, wt42, b2, nbr, feat, nullptr, out);
}